// Round 1
// baseline (256.974 us; speedup 1.0000x reference)
//
#include <hip/hip_runtime.h>

// Problem constants (match reference)
constexpr int Bn = 32;      // batch
constexpr int Nn = 512;     // logical qubits
constexpr int Qq = 512;     // physical qubits
constexpr int Ee = 4096;    // edges per batch

// ---------------------------------------------------------------------------
// Kernel 1: per-batch inverse edge-weight sum: inv_w[b] = 1/max(sum_e w, 1e-8)
// ---------------------------------------------------------------------------
__global__ __launch_bounds__(256) void k_sumw(const float* __restrict__ edge_w,
                                              float* __restrict__ inv_w) {
    int b = blockIdx.x;
    const float* w = edge_w + (size_t)b * Ee;
    float s = 0.f;
    for (int i = threadIdx.x; i < Ee; i += 256) s += w[i];
    // wave reduce (64 lanes)
    for (int off = 32; off; off >>= 1) s += __shfl_down(s, off);
    __shared__ float red[4];
    int wave = threadIdx.x >> 6, lane = threadIdx.x & 63;
    if (lane == 0) red[wave] = s;
    __syncthreads();
    if (threadIdx.x == 0) {
        float t = red[0] + red[1] + red[2] + red[3];
        inv_w[b] = 1.0f / fmaxf(t, 1e-8f);
    }
}

// ---------------------------------------------------------------------------
// Kernel 2: G = P_flat * Dswap, where P_flat is [B*N, Q], Dswap[k][j] =
//   3*max(d_hw[k][j]-1, 0).  Tiled fp32 GEMM, 64x64 tile, BK=16, 256 threads,
//   each thread computes a 4x4 sub-block.
// ---------------------------------------------------------------------------
__global__ __launch_bounds__(256) void k_gemm(const float* __restrict__ P,
                                              const float* __restrict__ d_hw,
                                              float* __restrict__ G) {
    __shared__ float As[16][64];   // [k][m]
    __shared__ float Bs[16][64];   // [k][n]
    const int bn = blockIdx.x;     // 0..7   (Q/64 columns)
    const int bm = blockIdx.y;     // 0..255 (B*N/64 rows)
    const int tid = threadIdx.x;
    const int tx = tid & 15;       // 0..15 -> 4 cols each
    const int ty = tid >> 4;       // 0..15 -> 4 rows each
    const int M0 = bm * 64, N0 = bn * 64;

    float acc[4][4] = {};

    for (int k0 = 0; k0 < Qq; k0 += 16) {
        // load A tile: 64 rows x 16 k
        #pragma unroll
        for (int i = tid; i < 64 * 16; i += 256) {
            int m = i >> 4, k = i & 15;
            As[k][m] = P[(size_t)(M0 + m) * Qq + (k0 + k)];
        }
        // load B tile: 16 k x 64 cols, with on-the-fly d_swap transform
        #pragma unroll
        for (int i = tid; i < 16 * 64; i += 256) {
            int k = i >> 6, n = i & 63;
            float d = d_hw[(size_t)(k0 + k) * Qq + (N0 + n)];
            Bs[k][n] = 3.0f * fmaxf(d - 1.0f, 0.0f);
        }
        __syncthreads();
        #pragma unroll
        for (int k = 0; k < 16; ++k) {
            float4 a4 = *(const float4*)&As[k][ty * 4];
            float4 b4 = *(const float4*)&Bs[k][tx * 4];
            float a[4] = {a4.x, a4.y, a4.z, a4.w};
            float bb[4] = {b4.x, b4.y, b4.z, b4.w};
            #pragma unroll
            for (int i = 0; i < 4; ++i)
                #pragma unroll
                for (int j = 0; j < 4; ++j)
                    acc[i][j] = fmaf(a[i], bb[j], acc[i][j]);
        }
        __syncthreads();
    }
    #pragma unroll
    for (int i = 0; i < 4; ++i) {
        float4 v = {acc[i][0], acc[i][1], acc[i][2], acc[i][3]};
        *(float4*)&G[(size_t)(M0 + ty * 4 + i) * Qq + (N0 + tx * 4)] = v;
    }
}

// ---------------------------------------------------------------------------
// Kernel 3: per-edge weighted dot:  sum_e w_e * dot(G[b,src], P[b,dst]) *
//   inv_w[b] / B, accumulated via one atomic per block.
//   1 wave per edge-group (EPW edges), 4 waves per block.
// ---------------------------------------------------------------------------
constexpr int EPW = 8;  // edges per wave
__global__ __launch_bounds__(256) void k_edges(const float* __restrict__ P,
                                               const float* __restrict__ G,
                                               const int* __restrict__ esrc,
                                               const int* __restrict__ edst,
                                               const float* __restrict__ ew,
                                               const float* __restrict__ inv_w,
                                               float* __restrict__ out) {
    const int wave = threadIdx.x >> 6;
    const int lane = threadIdx.x & 63;
    float local = 0.f;
    const int base = (blockIdx.x * 4 + wave) * EPW;
    #pragma unroll
    for (int t = 0; t < EPW; ++t) {
        int idx = base + t;          // global edge id in [0, B*E)
        int b = idx >> 12;           // / 4096
        size_t be = (size_t)idx;     // == b*Ee + e
        int s = esrc[be];
        int d = edst[be];
        float w = ew[be];
        const float4* gr = (const float4*)(G + ((size_t)b * Nn + s) * Qq);
        const float4* pr = (const float4*)(P + ((size_t)b * Nn + d) * Qq);
        float dot = 0.f;
        #pragma unroll
        for (int u = 0; u < 2; ++u) {
            float4 g = gr[lane + 64 * u];
            float4 p = pr[lane + 64 * u];
            dot += g.x * p.x + g.y * p.y + g.z * p.z + g.w * p.w;
        }
        local += w * dot * inv_w[b];
    }
    // wave reduce
    for (int off = 32; off; off >>= 1) local += __shfl_down(local, off);
    __shared__ float red[4];
    if (lane == 0) red[wave] = local;
    __syncthreads();
    if (threadIdx.x == 0) {
        float t = (red[0] + red[1] + red[2] + red[3]) * (1.0f / Bn);
        atomicAdd(out, t);
    }
}

// ---------------------------------------------------------------------------
extern "C" void kernel_launch(void* const* d_in, const int* in_sizes, int n_in,
                              void* d_out, int out_size, void* d_ws, size_t ws_size,
                              hipStream_t stream) {
    const float* P    = (const float*)d_in[0];   // [B,N,Q] f32
    const float* d_hw = (const float*)d_in[1];   // [Q,Q]   f32
    const int* esrc   = (const int*)d_in[2];     // [B,E]
    const int* edst   = (const int*)d_in[3];     // [B,E]
    const float* ew   = (const float*)d_in[4];   // [B,E]
    float* out = (float*)d_out;

    float* ws = (float*)d_ws;
    float* inv_w = ws;              // 32 floats
    float* G = ws + 256;            // [B*N, Q] f32 = 33.55 MB

    hipMemsetAsync(out, 0, sizeof(float), stream);

    k_sumw<<<dim3(Bn), dim3(256), 0, stream>>>(ew, inv_w);
    k_gemm<<<dim3(Qq / 64, (Bn * Nn) / 64), dim3(256), 0, stream>>>(P, d_hw, G);
    k_edges<<<dim3((Bn * Ee) / (4 * EPW)), dim3(256), 0, stream>>>(
        P, G, esrc, edst, ew, inv_w, out);
}

// Round 2
// 111.145 us; speedup vs baseline: 2.3121x; 2.3121x over previous
//
#include <hip/hip_runtime.h>

// Problem constants (match reference)
constexpr int Bn = 32;      // batch
constexpr int Nn = 512;     // logical qubits
constexpr int Qq = 512;     // physical qubits
constexpr int Ee = 4096;    // edges per batch
constexpr int Mtot = Bn * Nn;  // 16384 rows of P_flat

typedef short bf16x8 __attribute__((ext_vector_type(8)));
typedef float f32x4 __attribute__((ext_vector_type(4)));
typedef unsigned short u16;
typedef unsigned short u16x8 __attribute__((ext_vector_type(8)));

__device__ inline u16 f2bf(float f) {   // RNE float->bf16
    union { float f; unsigned u; } x; x.f = f;
    unsigned r = x.u + 0x7FFFu + ((x.u >> 16) & 1u);
    return (u16)(r >> 16);
}
__device__ inline float bf2f(u16 h) {
    union { unsigned u; float f; } x; x.u = ((unsigned)h) << 16;
    return x.f;
}
__device__ inline void gload_lds16(const u16* g, u16* l) {
    __builtin_amdgcn_global_load_lds(
        (const __attribute__((address_space(1))) unsigned int*)g,
        (__attribute__((address_space(3))) unsigned int*)l, 16, 0, 0);
}

// ---------------------------------------------------------------------------
// Kernel 1: inv_w[b] = 1/max(sum_e w, 1e-8)
// ---------------------------------------------------------------------------
__global__ __launch_bounds__(256) void k_sumw(const float* __restrict__ edge_w,
                                              float* __restrict__ inv_w) {
    int b = blockIdx.x;
    const float* w = edge_w + (size_t)b * Ee;
    float s = 0.f;
    for (int i = threadIdx.x; i < Ee; i += 256) s += w[i];
    for (int off = 32; off; off >>= 1) s += __shfl_down(s, off);
    __shared__ float red[4];
    int wave = threadIdx.x >> 6, lane = threadIdx.x & 63;
    if (lane == 0) red[wave] = s;
    __syncthreads();
    if (threadIdx.x == 0) {
        float t = red[0] + red[1] + red[2] + red[3];
        inv_w[b] = 1.0f / fmaxf(t, 1e-8f);
    }
}

// ---------------------------------------------------------------------------
// Kernel 2a: Dbf[q][r] = bf16( 3*max(d_hw-1,0) )   (symmetric transform)
// ---------------------------------------------------------------------------
__global__ __launch_bounds__(256) void k_prep_d(const float* __restrict__ d_hw,
                                                u16* __restrict__ Dbf) {
    int i = blockIdx.x * 256 + threadIdx.x;   // 4 elems per thread
    float4 v = ((const float4*)d_hw)[i];
    ushort4 o;
    o.x = f2bf(3.f * fmaxf(v.x - 1.f, 0.f));
    o.y = f2bf(3.f * fmaxf(v.y - 1.f, 0.f));
    o.z = f2bf(3.f * fmaxf(v.z - 1.f, 0.f));
    o.w = f2bf(3.f * fmaxf(v.w - 1.f, 0.f));
    ((ushort4*)Dbf)[i] = o;
}

// ---------------------------------------------------------------------------
// Kernel 2b: Pbf = bf16(P)   (8 elems per thread)
// ---------------------------------------------------------------------------
__global__ __launch_bounds__(256) void k_prep_p(const float* __restrict__ P,
                                                u16* __restrict__ Pbf) {
    size_t i = (size_t)blockIdx.x * 256 + threadIdx.x;
    float4 v0 = ((const float4*)P)[i * 2];
    float4 v1 = ((const float4*)P)[i * 2 + 1];
    u16x8 o;
    o[0] = f2bf(v0.x); o[1] = f2bf(v0.y); o[2] = f2bf(v0.z); o[3] = f2bf(v0.w);
    o[4] = f2bf(v1.x); o[5] = f2bf(v1.y); o[6] = f2bf(v1.z); o[7] = f2bf(v1.w);
    ((u16x8*)Pbf)[i] = o;
}

// ---------------------------------------------------------------------------
// Kernel 3: G = Pbf * Dbf  via MFMA 16x16x32 bf16, m97 structure.
//   A = Pbf [Mtot][512] row-major. B-fragment wants Bt[n][k]; d_swap is
//   SYMMETRIC so Bt rows are just Dbf rows -> both tiles stage identically.
//   128x128 tile, BK=32, 4 waves (2x2 of 64x64), global_load_lds width 16.
// ---------------------------------------------------------------------------
__global__ __launch_bounds__(256) void k_gemm(const u16* __restrict__ A,
                                              const u16* __restrict__ Bt,
                                              u16* __restrict__ G) {
    __shared__ u16 As[128 * 32];
    __shared__ u16 Bs[128 * 32];
    const int tid = threadIdx.x;
    const int lane = tid & 63;
    const int wave = tid >> 6;
    const int wm = wave >> 1, wn = wave & 1;
    const int M0 = blockIdx.y * 128, N0 = blockIdx.x * 128;

    // staging: thread t covers linear bytes o = p*4096 + t*16 of the [128][32]
    // bf16 tile; row = o/64B, col-shorts = (o%64)/2
    const int srow = tid >> 2;            // 0..63 (pass 0), +64 for pass 1
    const int scol = (tid & 3) * 8;

    const u16* gA = A + (size_t)(M0 + srow) * Qq + scol;
    const u16* gB = Bt + (size_t)(N0 + srow) * Qq + scol;

    u16* lA0 = As + wave * 512;           // pass0: byte offset wave*1024
    u16* lA1 = As + 2048 + wave * 512;    // pass1: +4096 B
    u16* lB0 = Bs + wave * 512;
    u16* lB1 = Bs + 2048 + wave * 512;

    f32x4 acc[4][4] = {};

    for (int k0 = 0; k0 < Qq; k0 += 32) {
        gload_lds16(gA + k0, lA0);
        gload_lds16(gA + (size_t)64 * Qq + k0, lA1);
        gload_lds16(gB + k0, lB0);
        gload_lds16(gB + (size_t)64 * Qq + k0, lB1);
        __syncthreads();   // drains vmcnt before barrier

        bf16x8 a[4], b[4];
        #pragma unroll
        for (int mi = 0; mi < 4; ++mi)
            a[mi] = *(const bf16x8*)&As[(wm * 64 + mi * 16 + (lane & 15)) * 32 + (lane >> 4) * 8];
        #pragma unroll
        for (int ni = 0; ni < 4; ++ni)
            b[ni] = *(const bf16x8*)&Bs[(wn * 64 + ni * 16 + (lane & 15)) * 32 + (lane >> 4) * 8];
        #pragma unroll
        for (int mi = 0; mi < 4; ++mi)
            #pragma unroll
            for (int ni = 0; ni < 4; ++ni)
                acc[mi][ni] = __builtin_amdgcn_mfma_f32_16x16x32_bf16(a[mi], b[ni], acc[mi][ni], 0, 0, 0);
        __syncthreads();
    }

    // epilogue: C/D layout col=lane&15, row=(lane>>4)*4+r  [guide m89]
    const int r0 = (lane >> 4) * 4;
    const int c = lane & 15;
    #pragma unroll
    for (int mi = 0; mi < 4; ++mi) {
        #pragma unroll
        for (int ni = 0; ni < 4; ++ni) {
            int row = M0 + wm * 64 + mi * 16 + r0;
            int col = N0 + wn * 64 + ni * 16 + c;
            #pragma unroll
            for (int r = 0; r < 4; ++r)
                G[(size_t)(row + r) * Qq + col] = f2bf(acc[mi][ni][r]);
        }
    }
}

// ---------------------------------------------------------------------------
// Kernel 4: per-edge weighted dot: sum_e w_e * dot(G[b,src], Pbf[b,dst]) *
//   inv_w[b] / B.  bf16 rows: 1 KB each, one uint4 (8 bf16) per lane.
// ---------------------------------------------------------------------------
constexpr int EPW = 8;  // edges per wave
__global__ __launch_bounds__(256) void k_edges(const u16* __restrict__ Pbf,
                                               const u16* __restrict__ G,
                                               const int* __restrict__ esrc,
                                               const int* __restrict__ edst,
                                               const float* __restrict__ ew,
                                               const float* __restrict__ inv_w,
                                               float* __restrict__ out) {
    const int wave = threadIdx.x >> 6;
    const int lane = threadIdx.x & 63;
    float local = 0.f;
    const int base = (blockIdx.x * 4 + wave) * EPW;
    #pragma unroll
    for (int t = 0; t < EPW; ++t) {
        int idx = base + t;          // global edge id in [0, B*E)
        int b = idx >> 12;           // / 4096
        int s = esrc[idx];
        int d = edst[idx];
        float w = ew[idx] * inv_w[b];
        const uint4* gr = (const uint4*)(G + ((size_t)b * Nn + s) * Qq);
        const uint4* pr = (const uint4*)(Pbf + ((size_t)b * Nn + d) * Qq);
        uint4 g = gr[lane];
        uint4 p = pr[lane];
        float dot = 0.f;
        #pragma unroll
        for (int cidx = 0; cidx < 4; ++cidx) {
            unsigned gu = ((const unsigned*)&g)[cidx];
            unsigned pu = ((const unsigned*)&p)[cidx];
            union { unsigned u; float f; } g0, g1, p0, p1;
            g0.u = gu << 16; g1.u = gu & 0xffff0000u;
            p0.u = pu << 16; p1.u = pu & 0xffff0000u;
            dot = fmaf(g0.f, p0.f, dot);
            dot = fmaf(g1.f, p1.f, dot);
        }
        local += w * dot;
    }
    for (int off = 32; off; off >>= 1) local += __shfl_down(local, off);
    __shared__ float red[4];
    if (lane == 0) red[wave] = local;
    __syncthreads();
    if (threadIdx.x == 0) {
        float t = (red[0] + red[1] + red[2] + red[3]) * (1.0f / Bn);
        atomicAdd(out, t);
    }
}

// ---------------------------------------------------------------------------
extern "C" void kernel_launch(void* const* d_in, const int* in_sizes, int n_in,
                              void* d_out, int out_size, void* d_ws, size_t ws_size,
                              hipStream_t stream) {
    const float* P    = (const float*)d_in[0];   // [B,N,Q] f32
    const float* d_hw = (const float*)d_in[1];   // [Q,Q]   f32
    const int* esrc   = (const int*)d_in[2];     // [B,E]
    const int* edst   = (const int*)d_in[3];     // [B,E]
    const float* ew   = (const float*)d_in[4];   // [B,E]
    float* out = (float*)d_out;

    char* ws = (char*)d_ws;
    float* inv_w = (float*)ws;                          // 32 f32 (1 KB reserved)
    u16* Pbf = (u16*)(ws + 1024);                       // [Mtot][512] bf16, 16.78 MB
    u16* Dbf = Pbf + (size_t)Mtot * Qq;                 // [512][512]  bf16, 0.52 MB
    u16* G   = Dbf + (size_t)Qq * Qq;                   // [Mtot][512] bf16, 16.78 MB

    hipMemsetAsync(out, 0, sizeof(float), stream);

    k_sumw<<<dim3(Bn), dim3(256), 0, stream>>>(ew, inv_w);
    k_prep_d<<<dim3(Qq * Qq / (4 * 256)), dim3(256), 0, stream>>>(d_hw, Dbf);
    k_prep_p<<<dim3((size_t)Mtot * Qq / (8 * 256)), dim3(256), 0, stream>>>(P, Pbf);
    k_gemm<<<dim3(Qq / 128, Mtot / 128), dim3(256), 0, stream>>>(Pbf, Dbf, G);
    k_edges<<<dim3((Bn * Ee) / (4 * EPW)), dim3(256), 0, stream>>>(
        Pbf, G, esrc, edst, ew, inv_w, out);
}

// Round 3
// 74.111 us; speedup vs baseline: 3.4674x; 1.4997x over previous
//
#include <hip/hip_runtime.h>

// Problem constants (match reference)
constexpr int Bn = 32;      // batch
constexpr int Nn = 512;     // logical qubits
constexpr int Qq = 512;     // physical qubits
constexpr int Ee = 4096;    // edges per batch
constexpr int Mtot = Bn * Nn;  // 16384 rows of P_flat

typedef short bf16x8 __attribute__((ext_vector_type(8)));
typedef float f32x4 __attribute__((ext_vector_type(4)));
typedef unsigned short u16;
typedef unsigned short u16x8 __attribute__((ext_vector_type(8)));

__device__ inline u16 f2bf(float f) {   // RNE float->bf16
    union { float f; unsigned u; } x; x.f = f;
    unsigned r = x.u + 0x7FFFu + ((x.u >> 16) & 1u);
    return (u16)(r >> 16);
}
__device__ inline float bf2f(u16 h) {
    union { unsigned u; float f; } x; x.u = ((unsigned)h) << 16;
    return x.f;
}
__device__ inline void gload_lds16(const u16* g, u16* l) {
    __builtin_amdgcn_global_load_lds(
        (const __attribute__((address_space(1))) unsigned int*)g,
        (__attribute__((address_space(3))) unsigned int*)l, 16, 0, 0);
}

// ---------------------------------------------------------------------------
// Kernel 1: inv_w[b] = 1/max(sum_e w, 1e-8)
// ---------------------------------------------------------------------------
__global__ __launch_bounds__(256) void k_sumw(const float* __restrict__ edge_w,
                                              float* __restrict__ inv_w) {
    int b = blockIdx.x;
    const float* w = edge_w + (size_t)b * Ee;
    float s = 0.f;
    for (int i = threadIdx.x; i < Ee; i += 256) s += w[i];
    for (int off = 32; off; off >>= 1) s += __shfl_down(s, off);
    __shared__ float red[4];
    int wave = threadIdx.x >> 6, lane = threadIdx.x & 63;
    if (lane == 0) red[wave] = s;
    __syncthreads();
    if (threadIdx.x == 0) {
        float t = red[0] + red[1] + red[2] + red[3];
        inv_w[b] = 1.0f / fmaxf(t, 1e-8f);
    }
}

// ---------------------------------------------------------------------------
// Kernel 2a: Dbf[q][r] = bf16( 3*max(d_hw-1,0) )   (symmetric transform)
// ---------------------------------------------------------------------------
__global__ __launch_bounds__(256) void k_prep_d(const float* __restrict__ d_hw,
                                                u16* __restrict__ Dbf) {
    int i = blockIdx.x * 256 + threadIdx.x;   // 4 elems per thread
    float4 v = ((const float4*)d_hw)[i];
    ushort4 o;
    o.x = f2bf(3.f * fmaxf(v.x - 1.f, 0.f));
    o.y = f2bf(3.f * fmaxf(v.y - 1.f, 0.f));
    o.z = f2bf(3.f * fmaxf(v.z - 1.f, 0.f));
    o.w = f2bf(3.f * fmaxf(v.w - 1.f, 0.f));
    ((ushort4*)Dbf)[i] = o;
}

// ---------------------------------------------------------------------------
// Kernel 2b: Pbf = bf16(P)   (8 elems per thread)
// ---------------------------------------------------------------------------
__global__ __launch_bounds__(256) void k_prep_p(const float* __restrict__ P,
                                                u16* __restrict__ Pbf) {
    size_t i = (size_t)blockIdx.x * 256 + threadIdx.x;
    float4 v0 = ((const float4*)P)[i * 2];
    float4 v1 = ((const float4*)P)[i * 2 + 1];
    u16x8 o;
    o[0] = f2bf(v0.x); o[1] = f2bf(v0.y); o[2] = f2bf(v0.z); o[3] = f2bf(v0.w);
    o[4] = f2bf(v1.x); o[5] = f2bf(v1.y); o[6] = f2bf(v1.z); o[7] = f2bf(v1.w);
    ((u16x8*)Pbf)[i] = o;
}

// ---------------------------------------------------------------------------
// Kernel 3: C = A * B^T via MFMA 16x16x32 bf16, m97 structure.
//   A [Mtot][512] row-major; B-fragment reads rows of Bt (Bt[n][k]).
//   PER_BATCH=false: Bt = Dbf (shared, symmetric) -> G = P*D
//   PER_BATCH=true : Bt = Pbf + batch*512*512    -> S = G*P_b^T
//   128x128 tile, BK=32, 4 waves (2x2 of 64x64), global_load_lds width 16.
// ---------------------------------------------------------------------------
template <bool PER_BATCH>
__global__ __launch_bounds__(256) void k_gemm(const u16* __restrict__ A,
                                              const u16* __restrict__ Bt,
                                              u16* __restrict__ C) {
    __shared__ u16 As[128 * 32];
    __shared__ u16 Bs[128 * 32];
    const int tid = threadIdx.x;
    const int lane = tid & 63;
    const int wave = tid >> 6;
    const int wm = wave >> 1, wn = wave & 1;
    const int M0 = blockIdx.y * 128, N0 = blockIdx.x * 128;

    // staging: thread t covers linear bytes o = p*4096 + t*16 of the [128][32]
    // bf16 tile; row = o/64B, col-shorts = (o%64)/2
    const int srow = tid >> 2;            // 0..63 (pass 0), +64 for pass 1
    const int scol = (tid & 3) * 8;

    const u16* Bbase = PER_BATCH ? Bt + ((size_t)(blockIdx.y >> 2) * Nn * Qq) : Bt;

    const u16* gA = A + (size_t)(M0 + srow) * Qq + scol;
    const u16* gB = Bbase + (size_t)(N0 + srow) * Qq + scol;

    u16* lA0 = As + wave * 512;           // pass0: byte offset wave*1024
    u16* lA1 = As + 2048 + wave * 512;    // pass1: +4096 B
    u16* lB0 = Bs + wave * 512;
    u16* lB1 = Bs + 2048 + wave * 512;

    f32x4 acc[4][4] = {};

    for (int k0 = 0; k0 < Qq; k0 += 32) {
        gload_lds16(gA + k0, lA0);
        gload_lds16(gA + (size_t)64 * Qq + k0, lA1);
        gload_lds16(gB + k0, lB0);
        gload_lds16(gB + (size_t)64 * Qq + k0, lB1);
        __syncthreads();   // drains vmcnt before barrier

        bf16x8 a[4], b[4];
        #pragma unroll
        for (int mi = 0; mi < 4; ++mi)
            a[mi] = *(const bf16x8*)&As[(wm * 64 + mi * 16 + (lane & 15)) * 32 + (lane >> 4) * 8];
        #pragma unroll
        for (int ni = 0; ni < 4; ++ni)
            b[ni] = *(const bf16x8*)&Bs[(wn * 64 + ni * 16 + (lane & 15)) * 32 + (lane >> 4) * 8];
        #pragma unroll
        for (int mi = 0; mi < 4; ++mi)
            #pragma unroll
            for (int ni = 0; ni < 4; ++ni)
                acc[mi][ni] = __builtin_amdgcn_mfma_f32_16x16x32_bf16(a[mi], b[ni], acc[mi][ni], 0, 0, 0);
        __syncthreads();
    }

    // epilogue: C/D layout col=lane&15, row=(lane>>4)*4+r  [guide m89]
    const int r0 = (lane >> 4) * 4;
    const int c = lane & 15;
    #pragma unroll
    for (int mi = 0; mi < 4; ++mi) {
        #pragma unroll
        for (int ni = 0; ni < 4; ++ni) {
            int row = M0 + wm * 64 + mi * 16 + r0;
            int col = N0 + wn * 64 + ni * 16 + c;
            #pragma unroll
            for (int r = 0; r < 4; ++r)
                C[(size_t)(row + r) * Qq + col] = f2bf(acc[mi][ni][r]);
        }
    }
}

// ---------------------------------------------------------------------------
// Kernel 4: per-edge lookup: out += sum_e w_e * S[b, src, dst] * inv_w[b] / B
//   One thread per edge; S element is a single bf16 load.
// ---------------------------------------------------------------------------
__global__ __launch_bounds__(256) void k_lookup(const u16* __restrict__ S,
                                                const int* __restrict__ esrc,
                                                const int* __restrict__ edst,
                                                const float* __restrict__ ew,
                                                const float* __restrict__ inv_w,
                                                float* __restrict__ out) {
    int idx = blockIdx.x * 256 + threadIdx.x;   // 0 .. B*E-1
    int b = idx >> 12;                          // / 4096
    int s = esrc[idx];
    int d = edst[idx];
    float w = ew[idx] * inv_w[b];
    float val = bf2f(S[((size_t)b << 18) + ((size_t)s << 9) + (size_t)d]);
    float local = w * val;
    for (int off = 32; off; off >>= 1) local += __shfl_down(local, off);
    __shared__ float red[4];
    int wave = threadIdx.x >> 6, lane = threadIdx.x & 63;
    if (lane == 0) red[wave] = local;
    __syncthreads();
    if (threadIdx.x == 0)
        atomicAdd(out, (red[0] + red[1] + red[2] + red[3]) * (1.0f / Bn));
}

// ---------------------------------------------------------------------------
extern "C" void kernel_launch(void* const* d_in, const int* in_sizes, int n_in,
                              void* d_out, int out_size, void* d_ws, size_t ws_size,
                              hipStream_t stream) {
    const float* P    = (const float*)d_in[0];   // [B,N,Q] f32
    const float* d_hw = (const float*)d_in[1];   // [Q,Q]   f32
    const int* esrc   = (const int*)d_in[2];     // [B,E]
    const int* edst   = (const int*)d_in[3];     // [B,E]
    const float* ew   = (const float*)d_in[4];   // [B,E]
    float* out = (float*)d_out;

    char* ws = (char*)d_ws;
    float* inv_w = (float*)ws;                          // 32 f32 (1 KB reserved)
    u16* Pbf = (u16*)(ws + 1024);                       // [Mtot][512] bf16, 16.78 MB
    u16* Dbf = Pbf + (size_t)Mtot * Qq;                 // [512][512]  bf16, 0.52 MB
    u16* G   = Dbf + (size_t)Qq * Qq;                   // [Mtot][512] bf16, 16.78 MB
    u16* S   = G + (size_t)Mtot * Qq;                   // [B][512][512] bf16, 16.78 MB

    hipMemsetAsync(out, 0, sizeof(float), stream);

    k_sumw<<<dim3(Bn), dim3(256), 0, stream>>>(ew, inv_w);
    k_prep_d<<<dim3(Qq * Qq / (4 * 256)), dim3(256), 0, stream>>>(d_hw, Dbf);
    k_prep_p<<<dim3((size_t)Mtot * Qq / (8 * 256)), dim3(256), 0, stream>>>(P, Pbf);
    k_gemm<false><<<dim3(Qq / 128, Mtot / 128), dim3(256), 0, stream>>>(Pbf, Dbf, G);
    k_gemm<true><<<dim3(Qq / 128, Mtot / 128), dim3(256), 0, stream>>>(G, Pbf, S);
    k_lookup<<<dim3((Bn * Ee) / 256), dim3(256), 0, stream>>>(
        S, esrc, edst, ew, inv_w, out);
}

// Round 4
// 69.869 us; speedup vs baseline: 3.6780x; 1.0607x over previous
//
#include <hip/hip_runtime.h>

// Problem constants (match reference)
constexpr int Bn = 32;      // batch
constexpr int Nn = 512;     // logical qubits
constexpr int Qq = 512;     // physical qubits
constexpr int Ee = 4096;    // edges per batch
constexpr int Mtot = Bn * Nn;  // 16384 rows of P_flat

typedef short bf16x8 __attribute__((ext_vector_type(8)));
typedef float f32x4 __attribute__((ext_vector_type(4)));
typedef unsigned short u16;
typedef unsigned short u16x8 __attribute__((ext_vector_type(8)));

__device__ inline u16 f2bf(float f) {   // RNE float->bf16
    union { float f; unsigned u; } x; x.f = f;
    unsigned r = x.u + 0x7FFFu + ((x.u >> 16) & 1u);
    return (u16)(r >> 16);
}
__device__ inline float bf2f(u16 h) {
    union { unsigned u; float f; } x; x.u = ((unsigned)h) << 16;
    return x.f;
}
__device__ inline void gload_lds16(const u16* g, u16* l) {
    __builtin_amdgcn_global_load_lds(
        (const __attribute__((address_space(1))) unsigned int*)g,
        (__attribute__((address_space(3))) unsigned int*)l, 16, 0, 0);
}

// ---------------------------------------------------------------------------
// Kernel 1: inv_w[b] = 1/max(sum_e w, 1e-8); block 0 also zeroes the output
// accumulator (replaces a separate memset dispatch; runs before k_lookup).
// ---------------------------------------------------------------------------
__global__ __launch_bounds__(256) void k_sumw(const float* __restrict__ edge_w,
                                              float* __restrict__ inv_w,
                                              float* __restrict__ out) {
    int b = blockIdx.x;
    const float* w = edge_w + (size_t)b * Ee;
    float s = 0.f;
    for (int i = threadIdx.x; i < Ee; i += 256) s += w[i];
    for (int off = 32; off; off >>= 1) s += __shfl_down(s, off);
    __shared__ float red[4];
    int wave = threadIdx.x >> 6, lane = threadIdx.x & 63;
    if (lane == 0) red[wave] = s;
    __syncthreads();
    if (threadIdx.x == 0) {
        float t = red[0] + red[1] + red[2] + red[3];
        inv_w[b] = 1.0f / fmaxf(t, 1e-8f);
        if (b == 0) out[0] = 0.f;
    }
}

// ---------------------------------------------------------------------------
// Kernel 2a: Dbf[q][r] = bf16( 3*max(d_hw-1,0) )   (symmetric transform)
// ---------------------------------------------------------------------------
__global__ __launch_bounds__(256) void k_prep_d(const float* __restrict__ d_hw,
                                                u16* __restrict__ Dbf) {
    int i = blockIdx.x * 256 + threadIdx.x;   // 4 elems per thread
    float4 v = ((const float4*)d_hw)[i];
    ushort4 o;
    o.x = f2bf(3.f * fmaxf(v.x - 1.f, 0.f));
    o.y = f2bf(3.f * fmaxf(v.y - 1.f, 0.f));
    o.z = f2bf(3.f * fmaxf(v.z - 1.f, 0.f));
    o.w = f2bf(3.f * fmaxf(v.w - 1.f, 0.f));
    ((ushort4*)Dbf)[i] = o;
}

// ---------------------------------------------------------------------------
// Kernel 2b: Pbf = bf16(P)   (8 elems per thread)
// ---------------------------------------------------------------------------
__global__ __launch_bounds__(256) void k_prep_p(const float* __restrict__ P,
                                                u16* __restrict__ Pbf) {
    size_t i = (size_t)blockIdx.x * 256 + threadIdx.x;
    float4 v0 = ((const float4*)P)[i * 2];
    float4 v1 = ((const float4*)P)[i * 2 + 1];
    u16x8 o;
    o[0] = f2bf(v0.x); o[1] = f2bf(v0.y); o[2] = f2bf(v0.z); o[3] = f2bf(v0.w);
    o[4] = f2bf(v1.x); o[5] = f2bf(v1.y); o[6] = f2bf(v1.z); o[7] = f2bf(v1.w);
    ((u16x8*)Pbf)[i] = o;
}

// ---------------------------------------------------------------------------
// Kernel 3: C = A * B^T via MFMA 16x16x32 bf16.
//   BM=64, BN=128, BK=32 -> grid (512/128) x (16384/64) = 4 x 256 = 1024
//   workgroups (~4 blocks/CU, 16 waves/CU: latency-hiding regime of m102).
//   4 waves in 2x2; each wave owns a 32x64 sub-tile (acc[2][4]).
//   A [Mtot][512] row-major; B-fragment reads rows of Bt (Bt[n][k]).
//   PER_BATCH=false: Bt = Dbf (shared, symmetric) -> G = P*D
//   PER_BATCH=true : Bt = Pbf + batch*512*512    -> S = G*P_b^T
// ---------------------------------------------------------------------------
template <bool PER_BATCH>
__global__ __launch_bounds__(256) void k_gemm(const u16* __restrict__ A,
                                              const u16* __restrict__ Bt,
                                              u16* __restrict__ C) {
    __shared__ u16 As[64 * 32];    // 4 KB
    __shared__ u16 Bs[128 * 32];   // 8 KB
    const int tid = threadIdx.x;
    const int lane = tid & 63;
    const int wave = tid >> 6;
    const int wm = wave >> 1, wn = wave & 1;     // 2x2 waves over (64,128)
    const int M0 = blockIdx.y * 64, N0 = blockIdx.x * 128;

    // staging: thread t covers linear bytes t*16 of a [rows][32] bf16 tile;
    // row = t>>2 (64 rows per 256-thread pass), col-shorts = (t&3)*8
    const int srow = tid >> 2;
    const int scol = (tid & 3) * 8;

    const u16* Bbase = PER_BATCH ? Bt + ((size_t)(blockIdx.y >> 3) * Nn * Qq) : Bt;

    const u16* gA = A + (size_t)(M0 + srow) * Qq + scol;
    const u16* gB = Bbase + (size_t)(N0 + srow) * Qq + scol;

    u16* lA0 = As + wave * 512;           // pass covers 64 rows (4 KB)
    u16* lB0 = Bs + wave * 512;           // pass 0: rows 0..63
    u16* lB1 = Bs + 2048 + wave * 512;    // pass 1: rows 64..127

    f32x4 acc[2][4] = {};

    for (int k0 = 0; k0 < Qq; k0 += 32) {
        gload_lds16(gA + k0, lA0);
        gload_lds16(gB + k0, lB0);
        gload_lds16(gB + (size_t)64 * Qq + k0, lB1);
        __syncthreads();   // drains vmcnt before barrier

        bf16x8 a[2], b[4];
        #pragma unroll
        for (int mi = 0; mi < 2; ++mi)
            a[mi] = *(const bf16x8*)&As[(wm * 32 + mi * 16 + (lane & 15)) * 32 + (lane >> 4) * 8];
        #pragma unroll
        for (int ni = 0; ni < 4; ++ni)
            b[ni] = *(const bf16x8*)&Bs[(wn * 64 + ni * 16 + (lane & 15)) * 32 + (lane >> 4) * 8];
        #pragma unroll
        for (int mi = 0; mi < 2; ++mi)
            #pragma unroll
            for (int ni = 0; ni < 4; ++ni)
                acc[mi][ni] = __builtin_amdgcn_mfma_f32_16x16x32_bf16(a[mi], b[ni], acc[mi][ni], 0, 0, 0);
        __syncthreads();
    }

    // epilogue: C/D layout col=lane&15, row=(lane>>4)*4+r  [guide m89]
    const int r0 = (lane >> 4) * 4;
    const int c = lane & 15;
    #pragma unroll
    for (int mi = 0; mi < 2; ++mi) {
        #pragma unroll
        for (int ni = 0; ni < 4; ++ni) {
            int row = M0 + wm * 32 + mi * 16 + r0;
            int col = N0 + wn * 64 + ni * 16 + c;
            #pragma unroll
            for (int r = 0; r < 4; ++r)
                C[(size_t)(row + r) * Qq + col] = f2bf(acc[mi][ni][r]);
        }
    }
}

// ---------------------------------------------------------------------------
// Kernel 4: per-edge lookup: out += sum_e w_e * S[b, src, dst] * inv_w[b] / B
//   One thread per edge; S element is a single bf16 load.
// ---------------------------------------------------------------------------
__global__ __launch_bounds__(256) void k_lookup(const u16* __restrict__ S,
                                                const int* __restrict__ esrc,
                                                const int* __restrict__ edst,
                                                const float* __restrict__ ew,
                                                const float* __restrict__ inv_w,
                                                float* __restrict__ out) {
    int idx = blockIdx.x * 256 + threadIdx.x;   // 0 .. B*E-1
    int b = idx >> 12;                          // / 4096
    int s = esrc[idx];
    int d = edst[idx];
    float w = ew[idx] * inv_w[b];
    float val = bf2f(S[((size_t)b << 18) + ((size_t)s << 9) + (size_t)d]);
    float local = w * val;
    for (int off = 32; off; off >>= 1) local += __shfl_down(local, off);
    __shared__ float red[4];
    int wave = threadIdx.x >> 6, lane = threadIdx.x & 63;
    if (lane == 0) red[wave] = local;
    __syncthreads();
    if (threadIdx.x == 0)
        atomicAdd(out, (red[0] + red[1] + red[2] + red[3]) * (1.0f / Bn));
}

// ---------------------------------------------------------------------------
extern "C" void kernel_launch(void* const* d_in, const int* in_sizes, int n_in,
                              void* d_out, int out_size, void* d_ws, size_t ws_size,
                              hipStream_t stream) {
    const float* P    = (const float*)d_in[0];   // [B,N,Q] f32
    const float* d_hw = (const float*)d_in[1];   // [Q,Q]   f32
    const int* esrc   = (const int*)d_in[2];     // [B,E]
    const int* edst   = (const int*)d_in[3];     // [B,E]
    const float* ew   = (const float*)d_in[4];   // [B,E]
    float* out = (float*)d_out;

    char* ws = (char*)d_ws;
    float* inv_w = (float*)ws;                          // 32 f32 (1 KB reserved)
    u16* Pbf = (u16*)(ws + 1024);                       // [Mtot][512] bf16, 16.78 MB
    u16* Dbf = Pbf + (size_t)Mtot * Qq;                 // [512][512]  bf16, 0.52 MB
    u16* G   = Dbf + (size_t)Qq * Qq;                   // [Mtot][512] bf16, 16.78 MB
    u16* S   = G + (size_t)Mtot * Qq;                   // [B][512][512] bf16, 16.78 MB

    k_sumw<<<dim3(Bn), dim3(256), 0, stream>>>(ew, inv_w, out);
    k_prep_d<<<dim3(Qq * Qq / (4 * 256)), dim3(256), 0, stream>>>(d_hw, Dbf);
    k_prep_p<<<dim3((size_t)Mtot * Qq / (8 * 256)), dim3(256), 0, stream>>>(P, Pbf);
    k_gemm<false><<<dim3(Qq / 128, Mtot / 64), dim3(256), 0, stream>>>(Pbf, Dbf, G);
    k_gemm<true><<<dim3(Qq / 128, Mtot / 64), dim3(256), 0, stream>>>(G, Pbf, S);
    k_lookup<<<dim3((Bn * Ee) / 256), dim3(256), 0, stream>>>(
        S, esrc, edst, ew, inv_w, out);
}